// Round 2
// baseline (286.628 us; speedup 1.0000x reference)
//
#include <hip/hip_runtime.h>

#define B_DIM 2
#define H_DIM 16
#define S_DIM 2048
#define D_DIM 64

constexpr int QB = 128;            // q rows per block (4 waves x 32)
constexpr int KB = 64;             // keys per tile
constexpr int NT = S_DIM / KB;     // 32 key tiles
constexpr float SCALE = 0.125f;    // 1/sqrt(64)
constexpr float FILL  = 1e-9f;

typedef __attribute__((ext_vector_type(8))) short short8;   // 8 bf16 (4 VGPRs)
typedef __attribute__((ext_vector_type(4))) float f32x4;

__device__ __forceinline__ unsigned short f2bf(float f) {
  union { float f; unsigned u; } v; v.f = f;
  unsigned u = v.u;
  u += 0x7FFFu + ((u >> 16) & 1u);   // round-to-nearest-even
  return (unsigned short)(u >> 16);
}

// stage one 64-key x 64-d K tile into swizzled LDS [key][d] bf16
__device__ __forceinline__ void stage_k_tile(const float* __restrict__ Kp,
                                             size_t bhS, int kt, int tid,
                                             unsigned short* sK)
{
  const int key = tid >> 2;               // 0..63
  const int dq  = (tid & 3) << 4;         // 0,16,32,48
  const float* src = Kp + (bhS + (size_t)(kt * KB + key)) * D_DIM + dq;
  float4 a0 = ((const float4*)src)[0];
  float4 a1 = ((const float4*)src)[1];
  float4 a2 = ((const float4*)src)[2];
  float4 a3 = ((const float4*)src)[3];
  short8 w0, w1;
  w0[0]=(short)f2bf(a0.x); w0[1]=(short)f2bf(a0.y); w0[2]=(short)f2bf(a0.z); w0[3]=(short)f2bf(a0.w);
  w0[4]=(short)f2bf(a1.x); w0[5]=(short)f2bf(a1.y); w0[6]=(short)f2bf(a1.z); w0[7]=(short)f2bf(a1.w);
  w1[0]=(short)f2bf(a2.x); w1[1]=(short)f2bf(a2.y); w1[2]=(short)f2bf(a2.z); w1[3]=(short)f2bf(a2.w);
  w1[4]=(short)f2bf(a3.x); w1[5]=(short)f2bf(a3.y); w1[6]=(short)f2bf(a3.z); w1[7]=(short)f2bf(a3.w);
  const int sw = (key & 7) << 3;          // XOR-swizzle (16B chunks) to kill bank conflicts
  *(short8*)&sK[key * 64 + (dq ^ sw)]       = w0;
  *(short8*)&sK[key * 64 + ((dq + 8) ^ sw)] = w1;
}

__global__ __launch_bounds__(256, 2)
void sdpa_kernel(const float* __restrict__ Qp, const float* __restrict__ Kp,
                 const float* __restrict__ Vp, const int* __restrict__ maskp,
                 float* __restrict__ ctx, float* __restrict__ attn)
{
  __shared__ __align__(16) unsigned short sK[KB * 64];      // [key][d] bf16, swizzled
  __shared__ __align__(16) unsigned short sV[64 * KB];      // [d][key] bf16, swizzled
  __shared__ __align__(16) unsigned short sP[4][32 * KB];   // per-wave P [q][key] bf16, swizzled
  __shared__ float scolv[KB];

  const int tid  = threadIdx.x;
  const int wave = tid >> 6;
  const int lane = tid & 63;
  const int c = lane & 15;      // fragment col index
  const int g = lane >> 4;      // fragment k-group / row-group

  const int bh = blockIdx.x >> 4;      // 32 (b,h) pairs
  const int qt = blockIdx.x & 15;      // 16 q-tiles of 128 rows
  const int q0 = qt * QB + wave * 32;  // this wave's first q row
  const size_t bhS = (size_t)bh * S_DIM;

  // ---- Q fragments, A-layout: row = lane&15, k = kk*32 + g*8 + j ----
  short8 qf[2][2];
  #pragma unroll
  for (int m = 0; m < 2; ++m)
    #pragma unroll
    for (int kk = 0; kk < 2; ++kk) {
      const float* src = Qp + (bhS + (size_t)(q0 + m*16 + c)) * D_DIM + kk*32 + g*8;
      float4 a = ((const float4*)src)[0];
      float4 b = ((const float4*)src)[1];
      short8 f;
      f[0]=(short)f2bf(a.x); f[1]=(short)f2bf(a.y); f[2]=(short)f2bf(a.z); f[3]=(short)f2bf(a.w);
      f[4]=(short)f2bf(b.x); f[5]=(short)f2bf(b.y); f[6]=(short)f2bf(b.z); f[7]=(short)f2bf(b.w);
      qf[m][kk] = f;
    }

  // row-valid flags for the D-layout rows this lane owns (row = m*16 + g*4 + e)
  float rvf[2][4];
  #pragma unroll
  for (int m = 0; m < 2; ++m)
    #pragma unroll
    for (int e = 0; e < 4; ++e)
      rvf[m][e] = maskp[bhS + q0 + m*16 + g*4 + e] ? 1.0f : 0.0f;

  float lsum[2][4];
  #pragma unroll
  for (int m = 0; m < 2; ++m)
    #pragma unroll
    for (int e = 0; e < 4; ++e) lsum[m][e] = 0.0f;

  // ================= pass 1: row sums of exp(s) =================
  for (int kt = 0; kt < NT; ++kt) {
    __syncthreads();
    stage_k_tile(Kp, bhS, kt, tid, sK);
    if (tid < KB) scolv[tid] = maskp[bhS + kt*KB + tid] ? 1.0f : 0.0f;
    __syncthreads();

    float cvf[4];
    #pragma unroll
    for (int n = 0; n < 4; ++n) cvf[n] = scolv[n*16 + c];

    short8 kf[4][2];
    #pragma unroll
    for (int n = 0; n < 4; ++n) {
      const int key = n*16 + c;
      const int sw = (key & 7) << 3;
      #pragma unroll
      for (int kk = 0; kk < 2; ++kk)
        kf[n][kk] = *(const short8*)&sK[key*64 + ((kk*32 + g*8) ^ sw)];
    }

    f32x4 sacc[2][4];
    #pragma unroll
    for (int m = 0; m < 2; ++m)
      #pragma unroll
      for (int n = 0; n < 4; ++n) sacc[m][n] = 0.0f;
    #pragma unroll
    for (int m = 0; m < 2; ++m)
      #pragma unroll
      for (int n = 0; n < 4; ++n)
        #pragma unroll
        for (int kk = 0; kk < 2; ++kk)
          sacc[m][n] = __builtin_amdgcn_mfma_f32_16x16x32_bf16(qf[m][kk], kf[n][kk], sacc[m][n], 0, 0, 0);

    #pragma unroll
    for (int m = 0; m < 2; ++m)
      #pragma unroll
      for (int n = 0; n < 4; ++n)
        #pragma unroll
        for (int e = 0; e < 4; ++e) {
          const bool valid = (rvf[m][e] * cvf[n]) != 0.0f;
          const float s = valid ? sacc[m][n][e] * SCALE : FILL;
          lsum[m][e] += __expf(s);
        }
  }

  // reduce across the 16 lanes of each group (cols) -> reciprocal row sum
  #pragma unroll
  for (int m = 0; m < 2; ++m)
    #pragma unroll
    for (int e = 0; e < 4; ++e) {
      float v = lsum[m][e];
      v += __shfl_xor(v, 1);
      v += __shfl_xor(v, 2);
      v += __shfl_xor(v, 4);
      v += __shfl_xor(v, 8);
      lsum[m][e] = 1.0f / v;
    }

  // ================= pass 2: recompute, write attn, PV =================
  f32x4 oacc[2][4];
  #pragma unroll
  for (int m = 0; m < 2; ++m)
    #pragma unroll
    for (int n = 0; n < 4; ++n) oacc[m][n] = 0.0f;

  unsigned short* const myP = sP[wave];

  for (int kt = 0; kt < NT; ++kt) {
    __syncthreads();
    stage_k_tile(Kp, bhS, kt, tid, sK);
    { // stage V transposed: sV[d][key] bf16, swizzled
      const int kp  = (tid & 31) << 1;     // even key 0..62
      const int dq8 = (tid >> 5) << 3;     // d octet 0..56
      const float* s0 = Vp + (bhS + (size_t)(kt * KB + kp)) * D_DIM + dq8;
      const float* s1 = s0 + D_DIM;
      float4 a0 = ((const float4*)s0)[0];
      float4 a1 = ((const float4*)s0)[1];
      float4 b0 = ((const float4*)s1)[0];
      float4 b1 = ((const float4*)s1)[1];
      float va[8] = {a0.x,a0.y,a0.z,a0.w,a1.x,a1.y,a1.z,a1.w};
      float vb[8] = {b0.x,b0.y,b0.z,b0.w,b1.x,b1.y,b1.z,b1.w};
      #pragma unroll
      for (int e = 0; e < 8; ++e) {
        const int d = dq8 + e;
        const unsigned pair = (unsigned)f2bf(va[e]) | ((unsigned)f2bf(vb[e]) << 16);
        *(unsigned*)&sV[d * KB + (kp ^ ((d & 7) << 3))] = pair;
      }
    }
    if (tid < KB) scolv[tid] = maskp[bhS + kt*KB + tid] ? 1.0f : 0.0f;
    __syncthreads();

    float cvf[4];
    #pragma unroll
    for (int n = 0; n < 4; ++n) cvf[n] = scolv[n*16 + c];

    short8 kf[4][2];
    #pragma unroll
    for (int n = 0; n < 4; ++n) {
      const int key = n*16 + c;
      const int sw = (key & 7) << 3;
      #pragma unroll
      for (int kk = 0; kk < 2; ++kk)
        kf[n][kk] = *(const short8*)&sK[key*64 + ((kk*32 + g*8) ^ sw)];
    }

    f32x4 sacc[2][4];
    #pragma unroll
    for (int m = 0; m < 2; ++m)
      #pragma unroll
      for (int n = 0; n < 4; ++n) sacc[m][n] = 0.0f;
    #pragma unroll
    for (int m = 0; m < 2; ++m)
      #pragma unroll
      for (int n = 0; n < 4; ++n)
        #pragma unroll
        for (int kk = 0; kk < 2; ++kk)
          sacc[m][n] = __builtin_amdgcn_mfma_f32_16x16x32_bf16(qf[m][kk], kf[n][kk], sacc[m][n], 0, 0, 0);

    // normalized p: store to attn (fp32) and to wave-private P LDS (bf16)
    #pragma unroll
    for (int m = 0; m < 2; ++m)
      #pragma unroll
      for (int n = 0; n < 4; ++n)
        #pragma unroll
        for (int e = 0; e < 4; ++e) {
          const int rl = m*16 + g*4 + e;
          const bool valid = (rvf[m][e] * cvf[n]) != 0.0f;
          const float s = valid ? sacc[m][n][e] * SCALE : FILL;
          const float p = __expf(s) * lsum[m][e];
          attn[(bhS + (size_t)(q0 + rl)) * S_DIM + (size_t)(kt*KB + n*16 + c)] = p;
          myP[rl*64 + ((n*16 + c) ^ ((rl & 7) << 3))] = f2bf(p);
        }

    // PV: A = P[q][key] from sP, B = V[key][d] from transposed sV
    short8 pf[2][2];
    #pragma unroll
    for (int m = 0; m < 2; ++m) {
      const int row = m*16 + c;
      const int sw = (row & 7) << 3;
      #pragma unroll
      for (int kk = 0; kk < 2; ++kk)
        pf[m][kk] = *(const short8*)&myP[row*64 + ((kk*32 + g*8) ^ sw)];
    }
    short8 vf[4][2];
    #pragma unroll
    for (int n = 0; n < 4; ++n) {
      const int d = n*16 + c;
      const int sw = (d & 7) << 3;
      #pragma unroll
      for (int kk = 0; kk < 2; ++kk)
        vf[n][kk] = *(const short8*)&sV[d*KB + ((kk*32 + g*8) ^ sw)];
    }
    #pragma unroll
    for (int m = 0; m < 2; ++m)
      #pragma unroll
      for (int n = 0; n < 4; ++n)
        #pragma unroll
        for (int kk = 0; kk < 2; ++kk)
          oacc[m][n] = __builtin_amdgcn_mfma_f32_16x16x32_bf16(pf[m][kk], vf[n][kk], oacc[m][n], 0, 0, 0);
  }

  // context write (already normalized since p was normalized before PV)
  #pragma unroll
  for (int m = 0; m < 2; ++m)
    #pragma unroll
    for (int n = 0; n < 4; ++n)
      #pragma unroll
      for (int e = 0; e < 4; ++e) {
        const int rl = m*16 + g*4 + e;
        ctx[(bhS + (size_t)(q0 + rl)) * D_DIM + (size_t)(n*16 + c)] = oacc[m][n][e];
      }
}

extern "C" void kernel_launch(void* const* d_in, const int* in_sizes, int n_in,
                              void* d_out, int out_size, void* d_ws, size_t ws_size,
                              hipStream_t stream) {
  const float* Q = (const float*)d_in[0];
  const float* K = (const float*)d_in[1];
  const float* V = (const float*)d_in[2];
  const int*   M = (const int*)d_in[3];
  float* ctx  = (float*)d_out;
  float* attn = ctx + (size_t)B_DIM * H_DIM * S_DIM * D_DIM;  // outputs concatenated: context, then attn
  dim3 grid(B_DIM * H_DIM * (S_DIM / QB));   // 512 blocks
  sdpa_kernel<<<grid, 256, 0, stream>>>(Q, K, V, M, ctx, attn);
}

// Round 3
// 225.805 us; speedup vs baseline: 1.2694x; 1.2694x over previous
//
#include <hip/hip_runtime.h>

#define B_DIM 2
#define H_DIM 16
#define S_DIM 2048
#define D_DIM 64

constexpr int QB = 128;            // q rows per block (4 waves x 32)
constexpr int KB = 64;             // keys per tile
constexpr int NT = S_DIM / KB;     // 32 key tiles
constexpr float CL2E = 0.18033688011112042f;  // (1/sqrt(64)) * log2(e)

typedef __attribute__((ext_vector_type(8))) short short8;   // 8 bf16
typedef __attribute__((ext_vector_type(4))) float f32x4;

__device__ __forceinline__ unsigned short f2bf(float f) {
  union { float f; unsigned u; } v; v.f = f;
  unsigned u = v.u;
  u += 0x7FFFu + ((u >> 16) & 1u);
  return (unsigned short)(u >> 16);
}

__device__ __forceinline__ unsigned pkbf(float lo, float hi) {
  unsigned r;
  asm("v_cvt_pk_bf16_f32 %0, %1, %2" : "=v"(r) : "v"(lo), "v"(hi));
  return r;
}

__device__ __forceinline__ float fexp2(float x) {
  float r;
  asm("v_exp_f32 %0, %1" : "=v"(r) : "v"(x));
  return r;
}

// raw barrier: drain LDS ops (cross-wave visibility) but NOT vmcnt —
// prefetch global loads stay in flight across the barrier (T14).
__device__ __forceinline__ void barrier_lds() {
  asm volatile("s_waitcnt lgkmcnt(0)" ::: "memory");
  __builtin_amdgcn_s_barrier();
  asm volatile("" ::: "memory");
}

__global__ __launch_bounds__(256, 2)
void sdpa_kernel(const float* __restrict__ Qp, const float* __restrict__ Kp,
                 const float* __restrict__ Vp, const int* __restrict__ maskp,
                 float* __restrict__ ctx, float* __restrict__ attn)
{
  __shared__ __align__(16) unsigned short sK[2][KB * 64];   // [buf][key][d] bf16, swizzled
  __shared__ __align__(16) unsigned short sV[2][64 * KB];   // [buf][d][key] bf16, swizzled
  __shared__ __align__(16) unsigned short sP[4][32 * KB];   // per-wave P [q][key] bf16, swizzled

  const int tid  = threadIdx.x;
  const int wave = tid >> 6;
  const int lane = tid & 63;
  const int c = lane & 15;      // fragment col index
  const int g = lane >> 4;      // fragment k-group / row-group

  const int bh = blockIdx.x >> 4;
  const int qt = blockIdx.x & 15;
  const int q0 = qt * QB + wave * 32;
  const size_t bhS = (size_t)bh * S_DIM;

  // staging coords
  const int key = tid >> 2;               // K: 0..63
  const int dq  = (tid & 3) << 4;         // K: 0,16,32,48
  const int kp  = (tid & 31) << 1;        // V: even key 0..62
  const int dq8 = (tid >> 5) << 3;        // V: d octet 0..56

  // ---- Q fragments, A-layout: row = lane&15, k = kk*32 + g*8 + j ----
  short8 qf[2][2];
  #pragma unroll
  for (int m = 0; m < 2; ++m)
    #pragma unroll
    for (int kk = 0; kk < 2; ++kk) {
      const float* src = Qp + (bhS + (size_t)(q0 + m*16 + c)) * D_DIM + kk*32 + g*8;
      float4 a = ((const float4*)src)[0];
      float4 b = ((const float4*)src)[1];
      union { unsigned u[4]; short8 s; } w;
      w.u[0] = pkbf(a.x, a.y); w.u[1] = pkbf(a.z, a.w);
      w.u[2] = pkbf(b.x, b.y); w.u[3] = pkbf(b.z, b.w);
      qf[m][kk] = w.s;
    }

  // fused row-mask * scale * log2e  (rows this lane owns in D-layout: m*16+g*4+e)
  float Crv[2][4];
  #pragma unroll
  for (int m = 0; m < 2; ++m)
    #pragma unroll
    for (int e = 0; e < 4; ++e)
      Crv[m][e] = maskp[bhS + q0 + m*16 + g*4 + e] ? CL2E : 0.0f;

  // prefetch registers
  float4 kr0, kr1, kr2, kr3;
  float4 vA0, vA1, vB0, vB1;
  int cvr[4];

  auto load_k = [&](int kt_) {
    const float* s = Kp + (bhS + (size_t)(kt_ * KB + key)) * D_DIM + dq;
    kr0 = ((const float4*)s)[0]; kr1 = ((const float4*)s)[1];
    kr2 = ((const float4*)s)[2]; kr3 = ((const float4*)s)[3];
  };
  auto load_v = [&](int kt_) {
    const float* s0 = Vp + (bhS + (size_t)(kt_ * KB + kp)) * D_DIM + dq8;
    vA0 = ((const float4*)s0)[0]; vA1 = ((const float4*)s0)[1];
    vB0 = ((const float4*)(s0 + D_DIM))[0]; vB1 = ((const float4*)(s0 + D_DIM))[1];
  };
  auto load_cv = [&](int kt_) {
    #pragma unroll
    for (int n = 0; n < 4; ++n) cvr[n] = maskp[bhS + kt_ * KB + n*16 + c];
  };
  auto write_k = [&](int buf) {
    union { unsigned u[4]; short8 s; } w0, w1;
    w0.u[0] = pkbf(kr0.x, kr0.y); w0.u[1] = pkbf(kr0.z, kr0.w);
    w0.u[2] = pkbf(kr1.x, kr1.y); w0.u[3] = pkbf(kr1.z, kr1.w);
    w1.u[0] = pkbf(kr2.x, kr2.y); w1.u[1] = pkbf(kr2.z, kr2.w);
    w1.u[2] = pkbf(kr3.x, kr3.y); w1.u[3] = pkbf(kr3.z, kr3.w);
    const int sw = (key & 7) << 3;
    *(short8*)&sK[buf][key * 64 + (dq ^ sw)]       = w0.s;
    *(short8*)&sK[buf][key * 64 + ((dq + 8) ^ sw)] = w1.s;
  };
  auto write_v = [&](int buf) {
    float fa[8], fb[8];
    *(float4*)&fa[0] = vA0; *(float4*)&fa[4] = vA1;
    *(float4*)&fb[0] = vB0; *(float4*)&fb[4] = vB1;
    #pragma unroll
    for (int e = 0; e < 8; ++e) {
      const int d = dq8 + e;
      *(unsigned*)&sV[buf][d * KB + (kp ^ ((d & 7) << 3))] = pkbf(fa[e], fb[e]);
    }
  };

  float lsum[2][4];
  #pragma unroll
  for (int m = 0; m < 2; ++m)
    #pragma unroll
    for (int e = 0; e < 4; ++e) lsum[m][e] = 0.0f;

  // ================= pass 1: row sums of exp(s) =================
  load_k(0); load_cv(0);
  for (int kt = 0; kt < NT; ++kt) {
    const int cur = kt & 1;
    write_k(cur);
    float cvf[4];
    #pragma unroll
    for (int n = 0; n < 4; ++n) cvf[n] = cvr[n] ? 1.0f : 0.0f;
    if (kt + 1 < NT) { load_k(kt + 1); load_cv(kt + 1); }
    barrier_lds();

    short8 kf[4][2];
    #pragma unroll
    for (int n = 0; n < 4; ++n) {
      const int k2 = n*16 + c;
      const int sw = (k2 & 7) << 3;
      #pragma unroll
      for (int kk = 0; kk < 2; ++kk)
        kf[n][kk] = *(const short8*)&sK[cur][k2*64 + ((kk*32 + g*8) ^ sw)];
    }

    f32x4 sacc[2][4];
    #pragma unroll
    for (int m = 0; m < 2; ++m)
      #pragma unroll
      for (int n = 0; n < 4; ++n) sacc[m][n] = 0.0f;
    __builtin_amdgcn_s_setprio(1);
    #pragma unroll
    for (int m = 0; m < 2; ++m)
      #pragma unroll
      for (int n = 0; n < 4; ++n)
        #pragma unroll
        for (int kk = 0; kk < 2; ++kk)
          sacc[m][n] = __builtin_amdgcn_mfma_f32_16x16x32_bf16(qf[m][kk], kf[n][kk], sacc[m][n], 0, 0, 0);
    __builtin_amdgcn_s_setprio(0);

    #pragma unroll
    for (int m = 0; m < 2; ++m)
      #pragma unroll
      for (int n = 0; n < 4; ++n)
        #pragma unroll
        for (int e = 0; e < 4; ++e)
          lsum[m][e] += fexp2(sacc[m][n][e] * Crv[m][e] * cvf[n]);
  }

  // reduce across 16 lanes (cols) -> reciprocal row sum
  #pragma unroll
  for (int m = 0; m < 2; ++m)
    #pragma unroll
    for (int e = 0; e < 4; ++e) {
      float v = lsum[m][e];
      v += __shfl_xor(v, 1);
      v += __shfl_xor(v, 2);
      v += __shfl_xor(v, 4);
      v += __shfl_xor(v, 8);
      lsum[m][e] = 1.0f / v;
    }

  // ================= pass 2: recompute, write attn, PV =================
  f32x4 oacc[2][4];
  #pragma unroll
  for (int m = 0; m < 2; ++m)
    #pragma unroll
    for (int n = 0; n < 4; ++n) oacc[m][n] = 0.0f;

  unsigned short* const myP = sP[wave];

  load_k(0); load_v(0); load_cv(0);
  for (int kt = 0; kt < NT; ++kt) {
    const int cur = kt & 1;
    write_k(cur);
    write_v(cur);
    float cvf[4];
    #pragma unroll
    for (int n = 0; n < 4; ++n) cvf[n] = cvr[n] ? 1.0f : 0.0f;
    if (kt + 1 < NT) { load_k(kt + 1); load_v(kt + 1); load_cv(kt + 1); }
    barrier_lds();

    short8 kf[4][2];
    #pragma unroll
    for (int n = 0; n < 4; ++n) {
      const int k2 = n*16 + c;
      const int sw = (k2 & 7) << 3;
      #pragma unroll
      for (int kk = 0; kk < 2; ++kk)
        kf[n][kk] = *(const short8*)&sK[cur][k2*64 + ((kk*32 + g*8) ^ sw)];
    }

    f32x4 sacc[2][4];
    #pragma unroll
    for (int m = 0; m < 2; ++m)
      #pragma unroll
      for (int n = 0; n < 4; ++n) sacc[m][n] = 0.0f;
    __builtin_amdgcn_s_setprio(1);
    #pragma unroll
    for (int m = 0; m < 2; ++m)
      #pragma unroll
      for (int n = 0; n < 4; ++n)
        #pragma unroll
        for (int kk = 0; kk < 2; ++kk)
          sacc[m][n] = __builtin_amdgcn_mfma_f32_16x16x32_bf16(qf[m][kk], kf[n][kk], sacc[m][n], 0, 0, 0);
    __builtin_amdgcn_s_setprio(0);

    // normalized p: write attn (fp32) + wave-private P (bf16) for PV
    #pragma unroll
    for (int m = 0; m < 2; ++m)
      #pragma unroll
      for (int n = 0; n < 4; ++n)
        #pragma unroll
        for (int e = 0; e < 4; ++e) {
          const int rl = m*16 + g*4 + e;
          const float p = fexp2(sacc[m][n][e] * Crv[m][e] * cvf[n]) * lsum[m][e];
          attn[(bhS + (size_t)(q0 + rl)) * S_DIM + (size_t)(kt*KB + n*16 + c)] = p;
          myP[rl*64 + ((n*16 + c) ^ ((rl & 7) << 3))] = f2bf(p);
        }

    // PV: A = P[q][key] from sP, B = V[key][d] from transposed sV
    short8 pf[2][2];
    #pragma unroll
    for (int m = 0; m < 2; ++m) {
      const int row = m*16 + c;
      const int sw = (row & 7) << 3;
      #pragma unroll
      for (int kk = 0; kk < 2; ++kk)
        pf[m][kk] = *(const short8*)&myP[row*64 + ((kk*32 + g*8) ^ sw)];
    }
    short8 vf[4][2];
    #pragma unroll
    for (int n = 0; n < 4; ++n) {
      const int d = n*16 + c;
      const int sw = (d & 7) << 3;
      #pragma unroll
      for (int kk = 0; kk < 2; ++kk)
        vf[n][kk] = *(const short8*)&sV[cur][d*KB + ((kk*32 + g*8) ^ sw)];
    }
    __builtin_amdgcn_s_setprio(1);
    #pragma unroll
    for (int m = 0; m < 2; ++m)
      #pragma unroll
      for (int n = 0; n < 4; ++n)
        #pragma unroll
        for (int kk = 0; kk < 2; ++kk)
          oacc[m][n] = __builtin_amdgcn_mfma_f32_16x16x32_bf16(pf[m][kk], vf[n][kk], oacc[m][n], 0, 0, 0);
    __builtin_amdgcn_s_setprio(0);
  }

  // context write
  #pragma unroll
  for (int m = 0; m < 2; ++m)
    #pragma unroll
    for (int n = 0; n < 4; ++n)
      #pragma unroll
      for (int e = 0; e < 4; ++e) {
        const int rl = m*16 + g*4 + e;
        ctx[(bhS + (size_t)(q0 + rl)) * D_DIM + (size_t)(n*16 + c)] = oacc[m][n][e];
      }
}

extern "C" void kernel_launch(void* const* d_in, const int* in_sizes, int n_in,
                              void* d_out, int out_size, void* d_ws, size_t ws_size,
                              hipStream_t stream) {
  const float* Q = (const float*)d_in[0];
  const float* K = (const float*)d_in[1];
  const float* V = (const float*)d_in[2];
  const int*   M = (const int*)d_in[3];
  float* ctx  = (float*)d_out;
  float* attn = ctx + (size_t)B_DIM * H_DIM * S_DIM * D_DIM;
  dim3 grid(B_DIM * H_DIM * (S_DIM / QB));   // 512 blocks
  sdpa_kernel<<<grid, 256, 0, stream>>>(Q, K, V, M, ctx, attn);
}

// Round 4
// 211.049 us; speedup vs baseline: 1.3581x; 1.0699x over previous
//
#include <hip/hip_runtime.h>

#define B_DIM 2
#define H_DIM 16
#define S_DIM 2048
#define D_DIM 64

constexpr int QB = 128;            // q rows per block (4 waves x 32)
constexpr int KB = 64;             // keys per tile
constexpr int NT = S_DIM / KB;     // 32 key tiles
constexpr float CL2E = 0.18033688011112042f;  // (1/sqrt(64)) * log2(e)

typedef __attribute__((ext_vector_type(8))) short short8;   // 8 bf16
typedef __attribute__((ext_vector_type(4))) float f32x4;
typedef __attribute__((ext_vector_type(2))) unsigned uint2v;

__device__ __forceinline__ unsigned pkbf(float lo, float hi) {
  unsigned r;
  asm("v_cvt_pk_bf16_f32 %0, %1, %2" : "=v"(r) : "v"(lo), "v"(hi));
  return r;
}

__device__ __forceinline__ float fexp2(float x) {
  float r;
  asm("v_exp_f32 %0, %1" : "=v"(r) : "v"(x));
  return r;
}

// drain LDS ops (cross-wave visibility) but NOT vmcnt — prefetch global
// loads stay in flight across the barrier (T14).
__device__ __forceinline__ void barrier_lds() {
  asm volatile("s_waitcnt lgkmcnt(0)" ::: "memory");
  __builtin_amdgcn_s_barrier();
  asm volatile("" ::: "memory");
}

__global__ __launch_bounds__(256, 2)
void sdpa_kernel(const float* __restrict__ Qp, const float* __restrict__ Kp,
                 const float* __restrict__ Vp, const int* __restrict__ maskp,
                 float* __restrict__ ctx, float* __restrict__ attn)
{
  __shared__ __align__(16) unsigned short sK[2][KB * 64];   // [buf][key][d] bf16, swizzled
  __shared__ __align__(16) unsigned short sV[2][64 * KB];   // [buf][d][key] bf16, swizzled
  __shared__ __align__(16) unsigned short sP[4][32 * KB];   // per-wave P [q][key] bf16, swizzled

  const int tid  = threadIdx.x;
  const int wave = tid >> 6;
  const int lane = tid & 63;
  const int c = lane & 15;      // fragment col index (q within 16)
  const int g = lane >> 4;      // fragment k-group / key-subgroup

  const int bh = blockIdx.x >> 4;
  const int qt = blockIdx.x & 15;
  const int q0 = qt * QB + wave * 32;
  const size_t bhS = (size_t)bh * S_DIM;

  // staging coords
  const int key = tid >> 2;               // K: 0..63
  const int dq  = (tid & 3) << 4;         // K: 0,16,32,48
  const int kp  = (tid & 31) << 1;        // V: even key 0..62
  const int dq8 = (tid >> 5) << 3;        // V: d octet 0..56

  // ---- Q fragments (B-operand): col=q=lane&15, k = kk*32 + g*8 + j ----
  short8 qf[2][2];
  #pragma unroll
  for (int m = 0; m < 2; ++m)
    #pragma unroll
    for (int kk = 0; kk < 2; ++kk) {
      const float* src = Qp + (bhS + (size_t)(q0 + m*16 + c)) * D_DIM + kk*32 + g*8;
      float4 a = ((const float4*)src)[0];
      float4 b = ((const float4*)src)[1];
      union { unsigned u[4]; short8 s; } w;
      w.u[0] = pkbf(a.x, a.y); w.u[1] = pkbf(a.z, a.w);
      w.u[2] = pkbf(b.x, b.y); w.u[3] = pkbf(b.z, b.w);
      qf[m][kk] = w.s;
    }

  // row(q)-mask * scale * log2e, per lane's q columns
  float rvS[2];
  #pragma unroll
  for (int m = 0; m < 2; ++m)
    rvS[m] = maskp[bhS + q0 + m*16 + c] ? CL2E : 0.0f;

  // prefetch registers
  float4 kr0, kr1, kr2, kr3;
  float4 vA0, vA1, vB0, vB1;
  int4 cv4[4];

  auto load_k = [&](int kt_) {
    const float* s = Kp + (bhS + (size_t)(kt_ * KB + key)) * D_DIM + dq;
    kr0 = ((const float4*)s)[0]; kr1 = ((const float4*)s)[1];
    kr2 = ((const float4*)s)[2]; kr3 = ((const float4*)s)[3];
  };
  auto load_v = [&](int kt_) {
    const float* s0 = Vp + (bhS + (size_t)(kt_ * KB + kp)) * D_DIM + dq8;
    vA0 = ((const float4*)s0)[0]; vA1 = ((const float4*)s0)[1];
    vB0 = ((const float4*)(s0 + D_DIM))[0]; vB1 = ((const float4*)(s0 + D_DIM))[1];
  };
  auto load_cv = [&](int kt_) {
    #pragma unroll
    for (int n = 0; n < 4; ++n)
      cv4[n] = *(const int4*)&maskp[bhS + kt_ * KB + n*16 + g*4];
  };
  auto write_k = [&](int buf) {
    union { unsigned u[4]; short8 s; } w0, w1;
    w0.u[0] = pkbf(kr0.x, kr0.y); w0.u[1] = pkbf(kr0.z, kr0.w);
    w0.u[2] = pkbf(kr1.x, kr1.y); w0.u[3] = pkbf(kr1.z, kr1.w);
    w1.u[0] = pkbf(kr2.x, kr2.y); w1.u[1] = pkbf(kr2.z, kr2.w);
    w1.u[2] = pkbf(kr3.x, kr3.y); w1.u[3] = pkbf(kr3.z, kr3.w);
    const int sw = (key & 7) << 3;
    *(short8*)&sK[buf][key * 64 + (dq ^ sw)]       = w0.s;
    *(short8*)&sK[buf][key * 64 + ((dq + 8) ^ sw)] = w1.s;
  };
  auto write_v = [&](int buf) {
    float fa[8], fb[8];
    *(float4*)&fa[0] = vA0; *(float4*)&fa[4] = vA1;
    *(float4*)&fb[0] = vB0; *(float4*)&fb[4] = vB1;
    #pragma unroll
    for (int e = 0; e < 8; ++e) {
      const int d = dq8 + e;
      *(unsigned*)&sV[buf][d * KB + (kp ^ ((d & 7) << 3))] = pkbf(fa[e], fb[e]);
    }
  };

  float lsum[2] = {0.0f, 0.0f};

  // ================= pass 1: row sums of exp(s) =================
  load_k(0); load_cv(0);
  for (int kt = 0; kt < NT; ++kt) {
    const int cur = kt & 1;
    write_k(cur);
    float cmf[4][4];
    #pragma unroll
    for (int n = 0; n < 4; ++n) {
      cmf[n][0] = cv4[n].x ? 1.0f : 0.0f;
      cmf[n][1] = cv4[n].y ? 1.0f : 0.0f;
      cmf[n][2] = cv4[n].z ? 1.0f : 0.0f;
      cmf[n][3] = cv4[n].w ? 1.0f : 0.0f;
    }
    if (kt + 1 < NT) { load_k(kt + 1); load_cv(kt + 1); }
    barrier_lds();

    short8 kf[4][2];
    #pragma unroll
    for (int n = 0; n < 4; ++n) {
      const int k2 = n*16 + c;
      const int sw = (k2 & 7) << 3;
      #pragma unroll
      for (int kk = 0; kk < 2; ++kk)
        kf[n][kk] = *(const short8*)&sK[cur][k2*64 + ((kk*32 + g*8) ^ sw)];
    }

    f32x4 sacc[4][2];   // [key-frag n][q-frag m]
    #pragma unroll
    for (int n = 0; n < 4; ++n)
      #pragma unroll
      for (int m = 0; m < 2; ++m) sacc[n][m] = 0.0f;
    __builtin_amdgcn_s_setprio(1);
    #pragma unroll
    for (int n = 0; n < 4; ++n)
      #pragma unroll
      for (int m = 0; m < 2; ++m)
        #pragma unroll
        for (int kk = 0; kk < 2; ++kk)
          sacc[n][m] = __builtin_amdgcn_mfma_f32_16x16x32_bf16(kf[n][kk], qf[m][kk], sacc[n][m], 0, 0, 0);
    __builtin_amdgcn_s_setprio(0);

    #pragma unroll
    for (int m = 0; m < 2; ++m)
      #pragma unroll
      for (int n = 0; n < 4; ++n)
        #pragma unroll
        for (int e = 0; e < 4; ++e)
          lsum[m] += fexp2(sacc[n][m][e] * (cmf[n][e] * rvS[m]));
  }

  // reduce over the 4 key-subgroups (lanes g) -> log2 of reciprocal row sum
  float Lm[2];
  #pragma unroll
  for (int m = 0; m < 2; ++m) {
    float v = lsum[m];
    v += __shfl_xor(v, 16);
    v += __shfl_xor(v, 32);
    Lm[m] = -__log2f(v);
  }

  // ================= pass 2: recompute, write attn, PV =================
  f32x4 oacc[2][4];
  #pragma unroll
  for (int m = 0; m < 2; ++m)
    #pragma unroll
    for (int n = 0; n < 4; ++n) oacc[m][n] = 0.0f;

  unsigned short* const myP = sP[wave];
  float* a0 = attn + (bhS + (size_t)(q0 + c)) * S_DIM + g*4;
  float* a1 = a0 + (size_t)16 * S_DIM;

  load_k(0); load_v(0); load_cv(0);
  for (int kt = 0; kt < NT; ++kt) {
    const int cur = kt & 1;
    write_k(cur);
    write_v(cur);
    float cmf[4][4];
    #pragma unroll
    for (int n = 0; n < 4; ++n) {
      cmf[n][0] = cv4[n].x ? 1.0f : 0.0f;
      cmf[n][1] = cv4[n].y ? 1.0f : 0.0f;
      cmf[n][2] = cv4[n].z ? 1.0f : 0.0f;
      cmf[n][3] = cv4[n].w ? 1.0f : 0.0f;
    }
    if (kt + 1 < NT) { load_k(kt + 1); load_v(kt + 1); load_cv(kt + 1); }
    barrier_lds();

    short8 kf[4][2];
    #pragma unroll
    for (int n = 0; n < 4; ++n) {
      const int k2 = n*16 + c;
      const int sw = (k2 & 7) << 3;
      #pragma unroll
      for (int kk = 0; kk < 2; ++kk)
        kf[n][kk] = *(const short8*)&sK[cur][k2*64 + ((kk*32 + g*8) ^ sw)];
    }

    f32x4 sacc[4][2];
    #pragma unroll
    for (int n = 0; n < 4; ++n)
      #pragma unroll
      for (int m = 0; m < 2; ++m) sacc[n][m] = 0.0f;
    __builtin_amdgcn_s_setprio(1);
    #pragma unroll
    for (int n = 0; n < 4; ++n)
      #pragma unroll
      for (int m = 0; m < 2; ++m)
        #pragma unroll
        for (int kk = 0; kk < 2; ++kk)
          sacc[n][m] = __builtin_amdgcn_mfma_f32_16x16x32_bf16(kf[n][kk], qf[m][kk], sacc[n][m], 0, 0, 0);
    __builtin_amdgcn_s_setprio(0);

    // p = exp2(s*comb + Lm): 4 consecutive keys per lane -> float4 nt store + b64 P write
    #pragma unroll
    for (int m = 0; m < 2; ++m) {
      float* am = m ? a1 : a0;
      #pragma unroll
      for (int n = 0; n < 4; ++n) {
        f32x4 pv;
        #pragma unroll
        for (int e = 0; e < 4; ++e)
          pv[e] = fexp2(__builtin_fmaf(sacc[n][m][e], cmf[n][e] * rvS[m], Lm[m]));
        __builtin_nontemporal_store(pv, (f32x4*)(am + n*16));
        const int row = m*16 + c;
        const int swk = (n*16 + g*4) ^ ((c & 7) << 3);
        uint2v pr; pr.x = pkbf(pv[0], pv[1]); pr.y = pkbf(pv[2], pv[3]);
        *(uint2v*)&myP[row*64 + swk] = pr;
      }
    }
    a0 += KB; a1 += KB;

    // PV: A = P[q][key] from sP, B = V[key][d] from transposed sV
    short8 pf[2][2];
    #pragma unroll
    for (int m = 0; m < 2; ++m) {
      const int row = m*16 + c;
      const int sw = (c & 7) << 3;
      #pragma unroll
      for (int kk = 0; kk < 2; ++kk)
        pf[m][kk] = *(const short8*)&myP[row*64 + ((kk*32 + g*8) ^ sw)];
    }
    short8 vf[4][2];
    #pragma unroll
    for (int n = 0; n < 4; ++n) {
      const int d = n*16 + c;
      const int sw = (d & 7) << 3;
      #pragma unroll
      for (int kk = 0; kk < 2; ++kk)
        vf[n][kk] = *(const short8*)&sV[cur][d*KB + ((kk*32 + g*8) ^ sw)];
    }
    __builtin_amdgcn_s_setprio(1);
    #pragma unroll
    for (int m = 0; m < 2; ++m)
      #pragma unroll
      for (int n = 0; n < 4; ++n)
        #pragma unroll
        for (int kk = 0; kk < 2; ++kk)
          oacc[m][n] = __builtin_amdgcn_mfma_f32_16x16x32_bf16(pf[m][kk], vf[n][kk], oacc[m][n], 0, 0, 0);
    __builtin_amdgcn_s_setprio(0);
  }

  // context write (D-layout: row q = m*16 + g*4 + e, col d = n*16 + c)
  #pragma unroll
  for (int m = 0; m < 2; ++m)
    #pragma unroll
    for (int n = 0; n < 4; ++n)
      #pragma unroll
      for (int e = 0; e < 4; ++e) {
        const int rl = m*16 + g*4 + e;
        ctx[(bhS + (size_t)(q0 + rl)) * D_DIM + (size_t)(n*16 + c)] = oacc[m][n][e];
      }
}

extern "C" void kernel_launch(void* const* d_in, const int* in_sizes, int n_in,
                              void* d_out, int out_size, void* d_ws, size_t ws_size,
                              hipStream_t stream) {
  const float* Q = (const float*)d_in[0];
  const float* K = (const float*)d_in[1];
  const float* V = (const float*)d_in[2];
  const int*   M = (const int*)d_in[3];
  float* ctx  = (float*)d_out;
  float* attn = ctx + (size_t)B_DIM * H_DIM * S_DIM * D_DIM;
  dim3 grid(B_DIM * H_DIM * (S_DIM / QB));   // 512 blocks
  sdpa_kernel<<<grid, 256, 0, stream>>>(Q, K, V, M, ctx, attn);
}

// Round 5
// 159.015 us; speedup vs baseline: 1.8025x; 1.3272x over previous
//
#include <hip/hip_runtime.h>

#define B_DIM 2
#define H_DIM 16
#define S_DIM 2048
#define D_DIM 64

constexpr int QB = 128;            // q rows per block (4 waves x 32)
constexpr int KB = 64;             // keys per tile
constexpr int NT = S_DIM / KB;     // 32 key tiles
constexpr float CL2E = 0.18033688011112042f;  // (1/sqrt(64)) * log2(e)

typedef __attribute__((ext_vector_type(8))) short short8;   // 8 bf16
typedef __attribute__((ext_vector_type(4))) float f32x4;
typedef __attribute__((ext_vector_type(2))) unsigned uint2v;

__device__ __forceinline__ unsigned pkbf(float lo, float hi) {
  unsigned r;
  asm("v_cvt_pk_bf16_f32 %0, %1, %2" : "=v"(r) : "v"(lo), "v"(hi));
  return r;
}

__device__ __forceinline__ float fexp2(float x) {
  float r;
  asm("v_exp_f32 %0, %1" : "=v"(r) : "v"(x));
  return r;
}

// drain LDS ops (cross-wave visibility) but NOT vmcnt — prefetch global
// loads stay in flight across the barrier (T14).
__device__ __forceinline__ void barrier_lds() {
  asm volatile("s_waitcnt lgkmcnt(0)" ::: "memory");
  __builtin_amdgcn_s_barrier();
  asm volatile("" ::: "memory");
}

__global__ __launch_bounds__(256, 2)
void sdpa_kernel(const float* __restrict__ Qp, const float* __restrict__ Kp,
                 const float* __restrict__ Vp, const int* __restrict__ maskp,
                 float* __restrict__ ctx, float* __restrict__ attn)
{
  __shared__ __align__(16) unsigned short sK[2][KB * 64];   // [buf][key][d] bf16, swizzled
  __shared__ __align__(16) unsigned short sV[2][64 * KB];   // [buf][d][key] bf16, swizzled
  __shared__ __align__(16) unsigned short sP[4][32 * KB];   // per-wave P [q][key] bf16, swizzled

  const int tid  = threadIdx.x;
  const int wave = tid >> 6;
  const int lane = tid & 63;
  const int c = lane & 15;      // fragment col index (q within 16)
  const int g = lane >> 4;      // fragment k-group / key-subgroup

  // XCD-aware bijective swizzle (gridDim=512, 512%8==0): each XCD gets a
  // contiguous chunk -> the 16 blocks sharing a (b,h) stay on one XCD's L2.
  const int bid = (blockIdx.x & 7) * 64 + (blockIdx.x >> 3);
  const int bh = bid >> 4;
  const int qt = bid & 15;
  const int q0 = qt * QB + wave * 32;
  const size_t bhS = (size_t)bh * S_DIM;

  // staging coords
  const int key = tid >> 2;               // K: 0..63
  const int dq  = (tid & 3) << 4;         // K: 0,16,32,48
  const int kp  = (tid & 31) << 1;        // V: even key 0..62
  const int dq8 = (tid >> 5) << 3;        // V: d octet 0..56

  // ---- Q fragments (B-operand): col=q=lane&15, k = kk*32 + g*8 + j ----
  short8 qf[2][2];
  #pragma unroll
  for (int m = 0; m < 2; ++m)
    #pragma unroll
    for (int kk = 0; kk < 2; ++kk) {
      const float* src = Qp + (bhS + (size_t)(q0 + m*16 + c)) * D_DIM + kk*32 + g*8;
      float4 a = ((const float4*)src)[0];
      float4 b = ((const float4*)src)[1];
      union { unsigned u[4]; short8 s; } w;
      w.u[0] = pkbf(a.x, a.y); w.u[1] = pkbf(a.z, a.w);
      w.u[2] = pkbf(b.x, b.y); w.u[3] = pkbf(b.z, b.w);
      qf[m][kk] = w.s;
    }

  // row(q)-mask * scale * log2e, per lane's q columns
  float rvS[2];
  #pragma unroll
  for (int m = 0; m < 2; ++m)
    rvS[m] = maskp[bhS + q0 + m*16 + c] ? CL2E : 0.0f;

  // prefetch registers
  float4 kr0, kr1, kr2, kr3;
  float4 vA0, vA1, vB0, vB1;
  int4 cv4[4];

  auto load_k = [&](int kt_) {
    const float* s = Kp + (bhS + (size_t)(kt_ * KB + key)) * D_DIM + dq;
    kr0 = ((const float4*)s)[0]; kr1 = ((const float4*)s)[1];
    kr2 = ((const float4*)s)[2]; kr3 = ((const float4*)s)[3];
  };
  auto load_v = [&](int kt_) {
    const float* s0 = Vp + (bhS + (size_t)(kt_ * KB + kp)) * D_DIM + dq8;
    vA0 = ((const float4*)s0)[0]; vA1 = ((const float4*)s0)[1];
    vB0 = ((const float4*)(s0 + D_DIM))[0]; vB1 = ((const float4*)(s0 + D_DIM))[1];
  };
  auto load_cv = [&](int kt_) {
    #pragma unroll
    for (int n = 0; n < 4; ++n)
      cv4[n] = *(const int4*)&maskp[bhS + kt_ * KB + n*16 + g*4];
  };
  auto write_k = [&](int buf) {
    union { unsigned u[4]; short8 s; } w0, w1;
    w0.u[0] = pkbf(kr0.x, kr0.y); w0.u[1] = pkbf(kr0.z, kr0.w);
    w0.u[2] = pkbf(kr1.x, kr1.y); w0.u[3] = pkbf(kr1.z, kr1.w);
    w1.u[0] = pkbf(kr2.x, kr2.y); w1.u[1] = pkbf(kr2.z, kr2.w);
    w1.u[2] = pkbf(kr3.x, kr3.y); w1.u[3] = pkbf(kr3.z, kr3.w);
    const int sw = (key & 7) << 3;
    *(short8*)&sK[buf][key * 64 + (dq ^ sw)]       = w0.s;
    *(short8*)&sK[buf][key * 64 + ((dq + 8) ^ sw)] = w1.s;
  };
  auto write_v = [&](int buf) {
    float fa[8], fb[8];
    *(float4*)&fa[0] = vA0; *(float4*)&fa[4] = vA1;
    *(float4*)&fb[0] = vB0; *(float4*)&fb[4] = vB1;
    #pragma unroll
    for (int e = 0; e < 8; ++e) {
      const int d = dq8 + e;
      *(unsigned*)&sV[buf][d * KB + (kp ^ ((d & 7) << 3))] = pkbf(fa[e], fb[e]);
    }
  };

  float lsum[2] = {0.0f, 0.0f};

  // ================= pass 1: row sums of exp(s) =================
  load_k(0); load_cv(0);
  for (int kt = 0; kt < NT; ++kt) {
    const int cur = kt & 1;
    write_k(cur);
    float cmf[4][4];
    #pragma unroll
    for (int n = 0; n < 4; ++n) {
      cmf[n][0] = cv4[n].x ? 1.0f : 0.0f;
      cmf[n][1] = cv4[n].y ? 1.0f : 0.0f;
      cmf[n][2] = cv4[n].z ? 1.0f : 0.0f;
      cmf[n][3] = cv4[n].w ? 1.0f : 0.0f;
    }
    if (kt + 1 < NT) { load_k(kt + 1); load_cv(kt + 1); }
    barrier_lds();

    short8 kf[4][2];
    #pragma unroll
    for (int n = 0; n < 4; ++n) {
      const int k2 = n*16 + c;
      const int sw = (k2 & 7) << 3;
      #pragma unroll
      for (int kk = 0; kk < 2; ++kk)
        kf[n][kk] = *(const short8*)&sK[cur][k2*64 + ((kk*32 + g*8) ^ sw)];
    }

    f32x4 sacc[4][2];   // [key-frag n][q-frag m]
    #pragma unroll
    for (int n = 0; n < 4; ++n)
      #pragma unroll
      for (int m = 0; m < 2; ++m) sacc[n][m] = 0.0f;
    __builtin_amdgcn_s_setprio(1);
    #pragma unroll
    for (int n = 0; n < 4; ++n)
      #pragma unroll
      for (int m = 0; m < 2; ++m)
        #pragma unroll
        for (int kk = 0; kk < 2; ++kk)
          sacc[n][m] = __builtin_amdgcn_mfma_f32_16x16x32_bf16(kf[n][kk], qf[m][kk], sacc[n][m], 0, 0, 0);
    __builtin_amdgcn_s_setprio(0);

    #pragma unroll
    for (int m = 0; m < 2; ++m)
      #pragma unroll
      for (int n = 0; n < 4; ++n)
        #pragma unroll
        for (int e = 0; e < 4; ++e)
          lsum[m] += fexp2(sacc[n][m][e] * (cmf[n][e] * rvS[m]));
  }

  // reduce over the 4 key-subgroups (lanes g) -> log2 of reciprocal row sum
  float Lm[2];
  #pragma unroll
  for (int m = 0; m < 2; ++m) {
    float v = lsum[m];
    v += __shfl_xor(v, 16);
    v += __shfl_xor(v, 32);
    Lm[m] = -__log2f(v);
  }

  // ================= pass 2: recompute, write attn, PV =================
  f32x4 oacc[2][4];
  #pragma unroll
  for (int m = 0; m < 2; ++m)
    #pragma unroll
    for (int n = 0; n < 4; ++n) oacc[m][n] = 0.0f;

  unsigned short* const myP = sP[wave];
  // attn copy-out coords: row = j*4 + rh, col = c16*4 (1KB contiguous per store)
  const int rh  = lane >> 4;
  const int c16 = lane & 15;
  float* const abase = attn + (bhS + (size_t)q0) * S_DIM;

  load_k(0); load_v(0); load_cv(0);
  for (int kt = 0; kt < NT; ++kt) {
    const int cur = kt & 1;
    write_k(cur);
    write_v(cur);
    float cmf[4][4];
    #pragma unroll
    for (int n = 0; n < 4; ++n) {
      cmf[n][0] = cv4[n].x ? 1.0f : 0.0f;
      cmf[n][1] = cv4[n].y ? 1.0f : 0.0f;
      cmf[n][2] = cv4[n].z ? 1.0f : 0.0f;
      cmf[n][3] = cv4[n].w ? 1.0f : 0.0f;
    }
    if (kt + 1 < NT) { load_k(kt + 1); load_v(kt + 1); load_cv(kt + 1); }
    barrier_lds();

    short8 kf[4][2];
    #pragma unroll
    for (int n = 0; n < 4; ++n) {
      const int k2 = n*16 + c;
      const int sw = (k2 & 7) << 3;
      #pragma unroll
      for (int kk = 0; kk < 2; ++kk)
        kf[n][kk] = *(const short8*)&sK[cur][k2*64 + ((kk*32 + g*8) ^ sw)];
    }

    f32x4 sacc[4][2];
    #pragma unroll
    for (int n = 0; n < 4; ++n)
      #pragma unroll
      for (int m = 0; m < 2; ++m) sacc[n][m] = 0.0f;
    __builtin_amdgcn_s_setprio(1);
    #pragma unroll
    for (int n = 0; n < 4; ++n)
      #pragma unroll
      for (int m = 0; m < 2; ++m)
        #pragma unroll
        for (int kk = 0; kk < 2; ++kk)
          sacc[n][m] = __builtin_amdgcn_mfma_f32_16x16x32_bf16(kf[n][kk], qf[m][kk], sacc[n][m], 0, 0, 0);
    __builtin_amdgcn_s_setprio(0);

    // p = exp2(s*comb + Lm) -> bf16 into wave-private sP (swizzled)
    #pragma unroll
    for (int m = 0; m < 2; ++m) {
      #pragma unroll
      for (int n = 0; n < 4; ++n) {
        f32x4 pv;
        #pragma unroll
        for (int e = 0; e < 4; ++e)
          pv[e] = fexp2(__builtin_fmaf(sacc[n][m][e], cmf[n][e] * rvS[m], Lm[m]));
        const int row = m*16 + c;
        const int swk = (n*16 + g*4) ^ ((c & 7) << 3);
        uint2v pr; pr.x = pkbf(pv[0], pv[1]); pr.y = pkbf(pv[2], pv[3]);
        *(uint2v*)&myP[row*64 + swk] = pr;
      }
    }

    // PV: A = P[q][key] from sP, B = V[key][d] from transposed sV
    short8 pf[2][2];
    #pragma unroll
    for (int m = 0; m < 2; ++m) {
      const int row = m*16 + c;
      const int sw = (c & 7) << 3;
      #pragma unroll
      for (int kk = 0; kk < 2; ++kk)
        pf[m][kk] = *(const short8*)&myP[row*64 + ((kk*32 + g*8) ^ sw)];
    }
    short8 vf[4][2];
    #pragma unroll
    for (int n = 0; n < 4; ++n) {
      const int d = n*16 + c;
      const int sw = (d & 7) << 3;
      #pragma unroll
      for (int kk = 0; kk < 2; ++kk)
        vf[n][kk] = *(const short8*)&sV[cur][d*KB + ((kk*32 + g*8) ^ sw)];
    }
    __builtin_amdgcn_s_setprio(1);
    #pragma unroll
    for (int m = 0; m < 2; ++m)
      #pragma unroll
      for (int n = 0; n < 4; ++n)
        #pragma unroll
        for (int kk = 0; kk < 2; ++kk)
          oacc[m][n] = __builtin_amdgcn_mfma_f32_16x16x32_bf16(pf[m][kk], vf[n][kk], oacc[m][n], 0, 0, 0);
    __builtin_amdgcn_s_setprio(0);

    // attn copy-out from sP: each store instr = 4 rows x 256B = 1KB contiguous
    {
      float* const at = abase + kt*KB;
      #pragma unroll
      for (int j = 0; j < 8; ++j) {
        const int r  = j*4 + rh;
        const int p8 = (c16 >> 1) ^ (r & 7);        // swizzled 16B-chunk position
        uint2v u = *(const uint2v*)&myP[r*64 + p8*8 + (c16 & 1)*4];
        union { unsigned iu; float f; } t0, t1, t2, t3;
        t0.iu = u.x << 16; t1.iu = u.x & 0xFFFF0000u;
        t2.iu = u.y << 16; t3.iu = u.y & 0xFFFF0000u;
        f32x4 o; o[0] = t0.f; o[1] = t1.f; o[2] = t2.f; o[3] = t3.f;
        __builtin_nontemporal_store(o, (f32x4*)(at + (size_t)r * S_DIM + c16*4));
      }
    }
  }

  // context write (D-layout: row q = m*16 + g*4 + e, col d = n*16 + c)
  #pragma unroll
  for (int m = 0; m < 2; ++m)
    #pragma unroll
    for (int n = 0; n < 4; ++n)
      #pragma unroll
      for (int e = 0; e < 4; ++e) {
        const int rl = m*16 + g*4 + e;
        ctx[(bhS + (size_t)(q0 + rl)) * D_DIM + (size_t)(n*16 + c)] = oacc[m][n][e];
      }
}

extern "C" void kernel_launch(void* const* d_in, const int* in_sizes, int n_in,
                              void* d_out, int out_size, void* d_ws, size_t ws_size,
                              hipStream_t stream) {
  const float* Q = (const float*)d_in[0];
  const float* K = (const float*)d_in[1];
  const float* V = (const float*)d_in[2];
  const int*   M = (const int*)d_in[3];
  float* ctx  = (float*)d_out;
  float* attn = ctx + (size_t)B_DIM * H_DIM * S_DIM * D_DIM;
  dim3 grid(B_DIM * H_DIM * (S_DIM / QB));   // 512 blocks
  sdpa_kernel<<<grid, 256, 0, stream>>>(Q, K, V, M, ctx, attn);
}